// Round 3
// baseline (594.233 us; speedup 1.0000x reference)
//
#include <hip/hip_runtime.h>
#include <hip/hip_bf16.h>
#include <math.h>

#define N_NODES 50000
#define N_EDGES 800000
#define HDIM 64

#define NBUCKET 392       // buckets of 128 nodes: 392*128 = 50176 >= 50000
#define BSHIFT  7
#define NLOC    128       // nodes per bucket
#define BCAP    3072      // mean 2048, sd ~45 -> ~22 sigma headroom

typedef short bf16x8 __attribute__((ext_vector_type(8)));
typedef float f32x4  __attribute__((ext_vector_type(4)));
typedef unsigned short ushort_t;

__device__ __forceinline__ ushort_t f2bf(float f) {
    __hip_bfloat16 b = __float2bfloat16(f);
    return *(ushort_t*)&b;
}

// ---------------------------------------------------------------------------
// Prep: [0,3125) features->bf16; [3125,3221) W transpose+convert;
// block 3221: zero bucketFill + scalar + done counter.
// ---------------------------------------------------------------------------
__global__ __launch_bounds__(256) void prep_kernel(
    const float* __restrict__ features, ushort_t* __restrict__ x_bf,
    const float* __restrict__ V, const float* __restrict__ lw,
    ushort_t* __restrict__ Wt, int* __restrict__ bucketFill,
    float* __restrict__ scalar, int* __restrict__ done)
{
    const int b = blockIdx.x;
    const int t = threadIdx.x;
    if (b < 3125) {
        const int i = b * 256 + t;                   // < 800000 float4s
        const float4 v = ((const float4*)features)[i];
        ushort4 o = { f2bf(v.x), f2bf(v.y), f2bf(v.z), f2bf(v.w) };
        *(ushort4*)&x_bf[(size_t)i * 4] = o;
    } else if (b < 3221) {
        const int e = (b - 3125) * 256 + t;          // < 24576
        const int l = e / 12288, r = e % 12288;
        const int n = r / 192, k = r % 192;
        const int sel = k >> 6, i = k & 63;
        const float val = (sel < 2) ? V[l * 8192 + sel * 4096 + i * 64 + n]
                                    : lw[l * 4096 + i * 64 + n];
        Wt[e] = f2bf(val);
    } else {
        for (int i = t; i < NBUCKET; i += 256) bucketFill[i] = 0;
        if (t == 0) { scalar[0] = 0.0f; done[0] = 0; }
    }
}

// ---------------------------------------------------------------------------
// K1: bucket scatter. Each block takes 2048 edges, LDS-counts 392 dst-buckets,
// reserves per-(block,bucket) space with one global atomicAdd per bucket,
// appends packed payloads: src(16) | etype(3)<<16 | dstloc(7)<<19.
// ---------------------------------------------------------------------------
__global__ __launch_bounds__(256) void bucket_scatter(
    const int* __restrict__ src, const int* __restrict__ dst,
    const int* __restrict__ etype, int* __restrict__ bucketFill,
    unsigned int* __restrict__ buf)
{
    __shared__ int cnt[NBUCKET];
    __shared__ int base[NBUCKET];
    const int t = threadIdx.x;
    for (int i = t; i < NBUCKET; i += 256) cnt[i] = 0;
    __syncthreads();

    int rank[8], bkt[8];
    unsigned pay[8];
    bool valid[8];
#pragma unroll
    for (int k = 0; k < 8; ++k) {
        const int e = blockIdx.x * 2048 + k * 256 + t;
        valid[k] = (e < N_EDGES);
        if (valid[k]) {
            const int d = dst[e];
            const int b = d >> BSHIFT;
            bkt[k] = b;
            pay[k] = (unsigned)src[e] | ((unsigned)etype[e] << 16)
                   | ((unsigned)(d & (NLOC - 1)) << 19);
            rank[k] = atomicAdd(&cnt[b], 1);
        }
    }
    __syncthreads();
    for (int i = t; i < NBUCKET; i += 256)
        base[i] = atomicAdd(&bucketFill[i], cnt[i]);
    __syncthreads();
#pragma unroll
    for (int k = 0; k < 8; ++k) {
        if (valid[k]) {
            const int pos = base[bkt[k]] + rank[k];
            if (pos < BCAP) buf[bkt[k] * BCAP + pos] = pay[k];
        }
    }
}

// ---------------------------------------------------------------------------
// K2: per-bucket sort. One block per bucket (392 blocks): hist over 128 local
// nodes, wave-scan, row_ptr write, final placement into the bucket's private
// contiguous window. Edges keep the dstloc bits (needed by edge-parallel agg).
// ---------------------------------------------------------------------------
__global__ __launch_bounds__(256) void bucket_sort(
    const unsigned int* __restrict__ buf, const int* __restrict__ bucketFill,
    unsigned int* __restrict__ edges, int* __restrict__ row_ptr)
{
    __shared__ int hist[NLOC];
    __shared__ int lscan[NLOC];
    __shared__ int cnt2[NLOC];
    __shared__ int sraw[448];
    __shared__ int sexc[448];
    const int b = blockIdx.x;
    const int t = threadIdx.x;

    if (t < NLOC) { hist[t] = 0; cnt2[t] = 0; }
    for (int i = t; i < 448; i += 256)
        sraw[i] = (i < NBUCKET) ? bucketFill[i] : 0;
    __syncthreads();

    // exclusive prefix over 392 bucket totals: wave 0, 7 chunks of 64
    if (t < 64) {
        int carry = 0;
        for (int c = 0; c < 7; ++c) {
            const int h = sraw[c * 64 + t];
            int x = h;
#pragma unroll
            for (int off = 1; off < 64; off <<= 1) {
                int u = __shfl_up(x, off, 64);
                if (t >= off) x += u;
            }
            sexc[c * 64 + t] = carry + x - h;
            carry += __shfl(x, 63, 64);
        }
    }
    __syncthreads();
    const int cntb = min(sraw[b], BCAP);
    const int bb   = sexc[b];

    // pass 1: node histogram, 4 loads in flight
    for (int i0 = t; i0 < cntb; i0 += 1024) {
        const bool v1 = i0 + 256 < cntb, v2 = i0 + 512 < cntb, v3 = i0 + 768 < cntb;
        const unsigned p0 = buf[b * BCAP + i0];
        unsigned p1 = 0, p2 = 0, p3 = 0;
        if (v1) p1 = buf[b * BCAP + i0 + 256];
        if (v2) p2 = buf[b * BCAP + i0 + 512];
        if (v3) p3 = buf[b * BCAP + i0 + 768];
        atomicAdd(&hist[p0 >> 19], 1);
        if (v1) atomicAdd(&hist[p1 >> 19], 1);
        if (v2) atomicAdd(&hist[p2 >> 19], 1);
        if (v3) atomicAdd(&hist[p3 >> 19], 1);
    }
    __syncthreads();

    // exclusive scan of 128 node counts: wave 0, 2 chunks of 64
    if (t < 64) {
        int carry = 0;
        for (int c = 0; c < 2; ++c) {
            const int h = hist[c * 64 + t];
            int x = h;
#pragma unroll
            for (int off = 1; off < 64; off <<= 1) {
                int u = __shfl_up(x, off, 64);
                if (t >= off) x += u;
            }
            lscan[c * 64 + t] = carry + x - h;
            carry += __shfl(x, 63, 64);
        }
    }
    __syncthreads();

    // row_ptr (coalesced)
    const int n0 = b << BSHIFT;
    if (t < NLOC) {
        const int g = n0 + t;
        if (g < N_NODES) row_ptr[g] = bb + lscan[t];
    }
    if (b == NBUCKET - 1 && t == 0) row_ptr[N_NODES] = bb + cntb;

    // pass 2: final placement, 4 loads in flight (keep dstloc bits!)
    for (int i0 = t; i0 < cntb; i0 += 1024) {
        const bool v1 = i0 + 256 < cntb, v2 = i0 + 512 < cntb, v3 = i0 + 768 < cntb;
        const unsigned p0 = buf[b * BCAP + i0];
        unsigned p1 = 0, p2 = 0, p3 = 0;
        if (v1) p1 = buf[b * BCAP + i0 + 256];
        if (v2) p2 = buf[b * BCAP + i0 + 512];
        if (v3) p3 = buf[b * BCAP + i0 + 768];
        {
            const int d = p0 >> 19;
            const int r = atomicAdd(&cnt2[d], 1);
            edges[bb + lscan[d] + r] = p0;
        }
        if (v1) { const int d = p1 >> 19; const int r = atomicAdd(&cnt2[d], 1);
                  edges[bb + lscan[d] + r] = p1; }
        if (v2) { const int d = p2 >> 19; const int r = atomicAdd(&cnt2[d], 1);
                  edges[bb + lscan[d] + r] = p2; }
        if (v3) { const int d = p3 >> 19; const int r = atomicAdd(&cnt2[d], 1);
                  edges[bb + lscan[d] + r] = p3; }
    }
}

// ---------------------------------------------------------------------------
// Fused layer v2 (edge-parallel aggregate):
// Phase A: one wave per edge per iteration -- 64 lanes load the full 128B
// source row (lane = feature), scale by broadcast comp pair, ds_add_f32 into
// suf[slot][feat] (slot = dst local to the block's 32 nodes). 4-edge unroll;
// wave-uniform same-dst fast path combines 8 atomics -> 2.
// Phase B: suf -> bf16 staging, MFMA h = U[32x192] @ W[192x64] + bias.
//  !FUSE: writes relu(h).  FUSE: h . fc_w -> scalar; last block sigmoid.
// ---------------------------------------------------------------------------
template <bool FUSE>
__global__ __launch_bounds__(256) void fused_layer(
    const ushort_t* __restrict__ xin,    // [N,64] bf16 (gather src + U tail)
    const unsigned int* __restrict__ edges,
    const int* __restrict__ row_ptr,
    const float* __restrict__ comp_l,    // [8,2] f32
    const ushort_t* __restrict__ Wt,     // [64,192] this layer (n-major)
    const float* __restrict__ bias,      // [64] f32
    const float* __restrict__ fcw,       // [N*64] (FUSE)
    ushort_t* __restrict__ xout,         // [N,64] (!FUSE)
    float* __restrict__ scalar,          // [1]    (FUSE)
    const float* __restrict__ fcb,       // [1]    (FUSE)
    int* __restrict__ done,              // [1]    (FUSE)
    float* __restrict__ outp)            // [1]    (FUSE)
{
    __shared__ __align__(16) float    suf[32 * 128];   // f32 accumulator, 16 KB
    __shared__ __align__(16) ushort_t su[32 * 200];    // bf16 staging, 12.8 KB
    __shared__ float sred[4];
    const int t    = threadIdx.x;
    const int tile = blockIdx.x;
    const int w    = t >> 6;
    const int lane = t & 63;
    const int c16  = lane & 15;
    const int quad = lane >> 4;
    const int grp  = t >> 3;             // node slot 0..31 (staging layout)
    const int fo   = t & 7;              // feature octet

    // preload phase-B operands early (VGPRs are free at this occupancy)
    bf16x8 wf[6];
#pragma unroll
    for (int kf = 0; kf < 6; ++kf)
        wf[kf] = *(const bf16x8*)&Wt[(w * 16 + c16) * 192 + kf * 32 + quad * 8];
    const float bv = bias[w * 16 + c16];

    // zero f32 accumulator (each thread 16 floats)
    {
        const f32x4 z = {0.f, 0.f, 0.f, 0.f};
        *(f32x4*)&suf[t * 16]      = z;
        *(f32x4*)&suf[t * 16 + 4]  = z;
        *(f32x4*)&suf[t * 16 + 8]  = z;
        *(f32x4*)&suf[t * 16 + 12] = z;
    }
    // stage U tail: parts [16..23] = x row
    {
        const int n = tile * 32 + grp;
        uint4 xt = {0u, 0u, 0u, 0u};
        if (n < N_NODES) xt = *(const uint4*)&xin[(size_t)n * 64 + fo * 8];
        *(uint4*)&su[grp * 200 + (16 + fo) * 8] = xt;
    }
    __syncthreads();

    // ---------- phase A: edge-parallel aggregate ----------
    const int nb   = tile * 32;
    const int nend = min(nb + 32, N_NODES);
    const int ebeg = row_ptr[nb];
    const int eend = row_ptr[nend];
    const int tloc = (tile & 3) * 32;

    for (int e0 = ebeg + w * 4; e0 < eend; e0 += 16) {
        unsigned p[4];
        float2 c[4];
        int sl[4];
#pragma unroll
        for (int k = 0; k < 4; ++k) {
            const int e = e0 + k;
            const unsigned pp = edges[(e < eend) ? e : (eend - 1)];
            p[k] = pp;
            float2 cc = *(const float2*)&comp_l[((pp >> 16) & 7u) * 2];
            if (e >= eend) { cc.x = 0.f; cc.y = 0.f; }
            c[k] = cc;
            sl[k] = (int)(pp >> 19) - tloc;
        }
        float f[4];
#pragma unroll
        for (int k = 0; k < 4; ++k) {
            const ushort_t us = xin[(size_t)(p[k] & 0xFFFFu) * 64 + lane];
            f[k] = __uint_as_float(((unsigned)us) << 16);
        }
        if (sl[0] == sl[1] && sl[1] == sl[2] && sl[2] == sl[3]) {
            // wave-uniform same-dst fast path: combine in registers
            float s0 = c[0].x * f[0] + c[1].x * f[1] + c[2].x * f[2] + c[3].x * f[3];
            float s1 = c[0].y * f[0] + c[1].y * f[1] + c[2].y * f[2] + c[3].y * f[3];
            atomicAdd(&suf[sl[0] * 128 + lane], s0);
            atomicAdd(&suf[sl[0] * 128 + 64 + lane], s1);
        } else {
#pragma unroll
            for (int k = 0; k < 4; ++k) {
                atomicAdd(&suf[sl[k] * 128 + lane], c[k].x * f[k]);
                atomicAdd(&suf[sl[k] * 128 + 64 + lane], c[k].y * f[k]);
            }
        }
    }
    __syncthreads();

    // ---------- convert suf -> bf16 staging (parts 0..15) ----------
    {
        const float4 u0 = *(const float4*)&suf[grp * 128 + fo * 8];
        const float4 u1 = *(const float4*)&suf[grp * 128 + fo * 8 + 4];
        const float4 v0 = *(const float4*)&suf[grp * 128 + 64 + fo * 8];
        const float4 v1 = *(const float4*)&suf[grp * 128 + 64 + fo * 8 + 4];
        uint4 o0, o1;
        o0.x = (unsigned)f2bf(u0.x) | ((unsigned)f2bf(u0.y) << 16);
        o0.y = (unsigned)f2bf(u0.z) | ((unsigned)f2bf(u0.w) << 16);
        o0.z = (unsigned)f2bf(u1.x) | ((unsigned)f2bf(u1.y) << 16);
        o0.w = (unsigned)f2bf(u1.z) | ((unsigned)f2bf(u1.w) << 16);
        o1.x = (unsigned)f2bf(v0.x) | ((unsigned)f2bf(v0.y) << 16);
        o1.y = (unsigned)f2bf(v0.z) | ((unsigned)f2bf(v0.w) << 16);
        o1.z = (unsigned)f2bf(v1.x) | ((unsigned)f2bf(v1.y) << 16);
        o1.w = (unsigned)f2bf(v1.z) | ((unsigned)f2bf(v1.w) << 16);
        *(uint4*)&su[grp * 200 + fo * 8]       = o0;
        *(uint4*)&su[grp * 200 + (8 + fo) * 8] = o1;
    }
    __syncthreads();

    // ---------- phase B: MFMA ----------
    float fsum = 0.f;
#pragma unroll
    for (int mt = 0; mt < 2; ++mt) {
        f32x4 acc = {bv, bv, bv, bv};
#pragma unroll
        for (int kf = 0; kf < 6; ++kf) {
            const bf16x8 af =
                *(const bf16x8*)&su[(mt * 16 + c16) * 200 + kf * 32 + quad * 8];
            acc = __builtin_amdgcn_mfma_f32_16x16x32_bf16(af, wf[kf], acc, 0, 0, 0);
        }
        const int nodeb = tile * 32 + mt * 16 + quad * 4;
        if (FUSE) {
#pragma unroll
            for (int r = 0; r < 4; ++r) {
                const int nn = nodeb + r;
                if (nn < N_NODES)
                    fsum += acc[r] * fcw[(size_t)nn * 64 + w * 16 + c16];
            }
        } else {
#pragma unroll
            for (int r = 0; r < 4; ++r) {
                const int nn = nodeb + r;
                if (nn < N_NODES)
                    xout[(size_t)nn * 64 + w * 16 + c16] = f2bf(fmaxf(acc[r], 0.f));
            }
        }
    }

    if (FUSE) {
#pragma unroll
        for (int off = 32; off; off >>= 1) fsum += __shfl_down(fsum, off, 64);
        if (lane == 0) sred[w] = fsum;
        __syncthreads();
        if (t == 0) {
            atomicAdd(scalar, sred[0] + sred[1] + sred[2] + sred[3]);
            __threadfence();
            const int ticket = atomicAdd(done, 1);
            if (ticket == (int)gridDim.x - 1) {
                const float v = atomicAdd(scalar, 0.0f) + fcb[0];
                outp[0] = 1.0f / (1.0f + expf(-v));
            }
        }
    }
}

// ---------------------------------------------------------------------------
extern "C" void kernel_launch(void* const* d_in, const int* in_sizes, int n_in,
                              void* d_out, int out_size, void* d_ws, size_t ws_size,
                              hipStream_t stream)
{
    const float* features = (const float*)d_in[0];  // [50000, 64]
    const float* V        = (const float*)d_in[1];  // [2, 2, 64, 64]
    const float* comp     = (const float*)d_in[2];  // [2, 8, 2]
    const float* loop_w   = (const float*)d_in[3];  // [2, 64, 64]
    const float* bias     = (const float*)d_in[4];  // [2, 64]
    const float* fc_w     = (const float*)d_in[5];  // [1, 50000*64]
    const float* fc_b     = (const float*)d_in[6];  // [1]
    const int*   src      = (const int*)d_in[7];
    const int*   dst      = (const int*)d_in[8];
    const int*   etype    = (const int*)d_in[9];
    float* out = (float*)d_out;

    char* ws = (char*)d_ws;
    ushort_t*     x_bf    = (ushort_t*)(ws);                 //  6,400,000 B
    ushort_t*     x1_bf   = (ushort_t*)(ws + 6400000);       //  6,400,000 B
    ushort_t*     Wt      = (ushort_t*)(ws + 12800000);      //     49,152 B
    float*        scalar  = (float*)   (ws + 12849152);      //          4 B
    int*          done    = (int*)     (ws + 12849156);      //          4 B
    int*          bucketFill = (int*)  (ws + 12849280);      //      1,568 B
    int*          row_ptr = (int*)     (ws + 12850944);      //    200,004 B
    unsigned int* edges   = (unsigned int*)(ws + 13051008);  //  3,200,000 B
    unsigned int* buf     = (unsigned int*)(ws + 16251008);  //  4,816,896 B
                                                             // end ~21.1 MB

    const int flBlocks = (N_NODES + 31) / 32;       // 1563
    const int k1Blocks = (N_EDGES + 2047) / 2048;   // 391

    // ---- prep (bf16 converts + zero counters) + bucketed CSR build ----
    prep_kernel<<<3222, 256, 0, stream>>>(features, x_bf, V, loop_w, Wt,
                                          bucketFill, scalar, done);
    bucket_scatter<<<k1Blocks, 256, 0, stream>>>(src, dst, etype, bucketFill, buf);
    bucket_sort<<<NBUCKET, 256, 0, stream>>>(buf, bucketFill, edges, row_ptr);

    // ---- layer 0 (aggregate + transform fused) ----
    fused_layer<false><<<flBlocks, 256, 0, stream>>>(
        x_bf, edges, row_ptr, comp, Wt, bias, nullptr, x1_bf,
        nullptr, nullptr, nullptr, nullptr);

    // ---- layer 1 (fused) + FC dot + last-block sigmoid ----
    fused_layer<true><<<flBlocks, 256, 0, stream>>>(
        x1_bf, edges, row_ptr, comp + 16, Wt + 12288, bias + 64, fc_w, nullptr,
        scalar, fc_b, done, out);
}

// Round 4
// 188.790 us; speedup vs baseline: 3.1476x; 3.1476x over previous
//
#include <hip/hip_runtime.h>
#include <hip/hip_bf16.h>
#include <math.h>

#define N_NODES 50000
#define N_EDGES 800000
#define HDIM 64

#define NBUCKET 392       // buckets of 128 nodes: 392*128 = 50176 >= 50000
#define BSHIFT  7
#define NLOC    128       // nodes per bucket
#define BCAP    3072      // mean 2048, sd ~45 -> ~22 sigma headroom

typedef short bf16x8 __attribute__((ext_vector_type(8)));
typedef float f32x4  __attribute__((ext_vector_type(4)));
typedef unsigned short ushort_t;

__device__ __forceinline__ ushort_t f2bf(float f) {
    __hip_bfloat16 b = __float2bfloat16(f);
    return *(ushort_t*)&b;
}

// ---------------------------------------------------------------------------
// Prep: [0,3125) features->bf16; [3125,3221) W transpose+convert;
// block 3221: zero bucketFill + scalar + done counter.
// ---------------------------------------------------------------------------
__global__ __launch_bounds__(256) void prep_kernel(
    const float* __restrict__ features, ushort_t* __restrict__ x_bf,
    const float* __restrict__ V, const float* __restrict__ lw,
    ushort_t* __restrict__ Wt, int* __restrict__ bucketFill,
    float* __restrict__ scalar, int* __restrict__ done)
{
    const int b = blockIdx.x;
    const int t = threadIdx.x;
    if (b < 3125) {
        const int i = b * 256 + t;                   // < 800000 float4s
        const float4 v = ((const float4*)features)[i];
        ushort4 o = { f2bf(v.x), f2bf(v.y), f2bf(v.z), f2bf(v.w) };
        *(ushort4*)&x_bf[(size_t)i * 4] = o;
    } else if (b < 3221) {
        const int e = (b - 3125) * 256 + t;          // < 24576
        const int l = e / 12288, r = e % 12288;
        const int n = r / 192, k = r % 192;
        const int sel = k >> 6, i = k & 63;
        const float val = (sel < 2) ? V[l * 8192 + sel * 4096 + i * 64 + n]
                                    : lw[l * 4096 + i * 64 + n];
        Wt[e] = f2bf(val);
    } else {
        for (int i = t; i < NBUCKET; i += 256) bucketFill[i] = 0;
        if (t == 0) { scalar[0] = 0.0f; done[0] = 0; }
    }
}

// ---------------------------------------------------------------------------
// K1: bucket scatter. Each block takes 2048 edges, LDS-counts 392 dst-buckets,
// reserves per-(block,bucket) space with one global atomicAdd per bucket,
// appends packed payloads: src(16) | etype(3)<<16 | dstloc(7)<<19.
// ---------------------------------------------------------------------------
__global__ __launch_bounds__(256) void bucket_scatter(
    const int* __restrict__ src, const int* __restrict__ dst,
    const int* __restrict__ etype, int* __restrict__ bucketFill,
    unsigned int* __restrict__ buf)
{
    __shared__ int cnt[NBUCKET];
    __shared__ int base[NBUCKET];
    const int t = threadIdx.x;
    for (int i = t; i < NBUCKET; i += 256) cnt[i] = 0;
    __syncthreads();

    int rank[8], bkt[8];
    unsigned pay[8];
    bool valid[8];
#pragma unroll
    for (int k = 0; k < 8; ++k) {
        const int e = blockIdx.x * 2048 + k * 256 + t;
        valid[k] = (e < N_EDGES);
        if (valid[k]) {
            const int d = dst[e];
            const int b = d >> BSHIFT;
            bkt[k] = b;
            pay[k] = (unsigned)src[e] | ((unsigned)etype[e] << 16)
                   | ((unsigned)(d & (NLOC - 1)) << 19);
            rank[k] = atomicAdd(&cnt[b], 1);
        }
    }
    __syncthreads();
    for (int i = t; i < NBUCKET; i += 256)
        base[i] = atomicAdd(&bucketFill[i], cnt[i]);
    __syncthreads();
#pragma unroll
    for (int k = 0; k < 8; ++k) {
        if (valid[k]) {
            const int pos = base[bkt[k]] + rank[k];
            if (pos < BCAP) buf[bkt[k] * BCAP + pos] = pay[k];
        }
    }
}

// ---------------------------------------------------------------------------
// K2: per-bucket sort. One block per bucket (392 blocks): hist over 128 local
// nodes, wave-scan, row_ptr write, final placement into the bucket's private
// contiguous window. 4 global loads in flight per pass.
// ---------------------------------------------------------------------------
__global__ __launch_bounds__(256) void bucket_sort(
    const unsigned int* __restrict__ buf, const int* __restrict__ bucketFill,
    unsigned int* __restrict__ edges, int* __restrict__ row_ptr)
{
    __shared__ int hist[NLOC];
    __shared__ int lscan[NLOC];
    __shared__ int cnt2[NLOC];
    __shared__ int sraw[448];
    __shared__ int sexc[448];
    const int b = blockIdx.x;
    const int t = threadIdx.x;

    if (t < NLOC) { hist[t] = 0; cnt2[t] = 0; }
    for (int i = t; i < 448; i += 256)
        sraw[i] = (i < NBUCKET) ? bucketFill[i] : 0;
    __syncthreads();

    // exclusive prefix over 392 bucket totals: wave 0, 7 chunks of 64
    if (t < 64) {
        int carry = 0;
        for (int c = 0; c < 7; ++c) {
            const int h = sraw[c * 64 + t];
            int x = h;
#pragma unroll
            for (int off = 1; off < 64; off <<= 1) {
                int u = __shfl_up(x, off, 64);
                if (t >= off) x += u;
            }
            sexc[c * 64 + t] = carry + x - h;
            carry += __shfl(x, 63, 64);
        }
    }
    __syncthreads();
    const int cntb = min(sraw[b], BCAP);
    const int bb   = sexc[b];

    // pass 1: node histogram, 4 loads in flight
    for (int i0 = t; i0 < cntb; i0 += 1024) {
        const bool v1 = i0 + 256 < cntb, v2 = i0 + 512 < cntb, v3 = i0 + 768 < cntb;
        const unsigned p0 = buf[b * BCAP + i0];
        unsigned p1 = 0, p2 = 0, p3 = 0;
        if (v1) p1 = buf[b * BCAP + i0 + 256];
        if (v2) p2 = buf[b * BCAP + i0 + 512];
        if (v3) p3 = buf[b * BCAP + i0 + 768];
        atomicAdd(&hist[p0 >> 19], 1);
        if (v1) atomicAdd(&hist[p1 >> 19], 1);
        if (v2) atomicAdd(&hist[p2 >> 19], 1);
        if (v3) atomicAdd(&hist[p3 >> 19], 1);
    }
    __syncthreads();

    // exclusive scan of 128 node counts: wave 0, 2 chunks of 64
    if (t < 64) {
        int carry = 0;
        for (int c = 0; c < 2; ++c) {
            const int h = hist[c * 64 + t];
            int x = h;
#pragma unroll
            for (int off = 1; off < 64; off <<= 1) {
                int u = __shfl_up(x, off, 64);
                if (t >= off) x += u;
            }
            lscan[c * 64 + t] = carry + x - h;
            carry += __shfl(x, 63, 64);
        }
    }
    __syncthreads();

    // row_ptr (coalesced)
    const int n0 = b << BSHIFT;
    if (t < NLOC) {
        const int g = n0 + t;
        if (g < N_NODES) row_ptr[g] = bb + lscan[t];
    }
    if (b == NBUCKET - 1 && t == 0) row_ptr[N_NODES] = bb + cntb;

    // pass 2: final placement, 4 loads in flight
    for (int i0 = t; i0 < cntb; i0 += 1024) {
        const bool v1 = i0 + 256 < cntb, v2 = i0 + 512 < cntb, v3 = i0 + 768 < cntb;
        const unsigned p0 = buf[b * BCAP + i0];
        unsigned p1 = 0, p2 = 0, p3 = 0;
        if (v1) p1 = buf[b * BCAP + i0 + 256];
        if (v2) p2 = buf[b * BCAP + i0 + 512];
        if (v3) p3 = buf[b * BCAP + i0 + 768];
        {
            const int d = p0 >> 19;
            const int r = atomicAdd(&cnt2[d], 1);
            edges[bb + lscan[d] + r] = p0;
        }
        if (v1) { const int d = p1 >> 19; const int r = atomicAdd(&cnt2[d], 1);
                  edges[bb + lscan[d] + r] = p1; }
        if (v2) { const int d = p2 >> 19; const int r = atomicAdd(&cnt2[d], 1);
                  edges[bb + lscan[d] + r] = p2; }
        if (v3) { const int d = p3 >> 19; const int r = atomicAdd(&cnt2[d], 1);
                  edges[bb + lscan[d] + r] = p3; }
    }
}

// ---------------------------------------------------------------------------
// Aggregate v4 (max-concurrency): 16-lane group per node, lane owns 4 feats
// (uint2 8B gathers), 4 nodes/wave, 16 nodes/block -> 3125 blocks, 12500
// waves (2x v2). Zero LDS accumulation, no cross-lane ops, VGPR-lean so
// occupancy is wave-slot-bound, not resource-bound. 4 edges in flight/lane.
// ---------------------------------------------------------------------------
__global__ __launch_bounds__(256) void aggregate_v4(
    const ushort_t* __restrict__ x,      // [N,64] bf16
    const unsigned int* __restrict__ edges,
    const int* __restrict__ row_ptr,
    const float* __restrict__ comp_l,    // [8,2] f32
    ushort_t* __restrict__ y)            // [N,128] bf16
{
    __shared__ float scomp[16];
    const int t = threadIdx.x;
    if (t < 16) scomp[t] = comp_l[t];
    __syncthreads();

    const int lane = t & 63;
    const int wv   = t >> 6;
    const int g    = lane >> 4;          // node slot within wave (0..3)
    const int fq   = lane & 15;          // feature quad: feats [fq*4, fq*4+4)
    const int n    = blockIdx.x * 16 + wv * 4 + g;   // 3125*16 = 50000 exact

    const int beg = row_ptr[n];
    const int end = row_ptr[n + 1];

    float a0[4], a1[4];
#pragma unroll
    for (int i = 0; i < 4; ++i) { a0[i] = 0.f; a1[i] = 0.f; }

    for (int j = beg; j < end; j += 4) {
        unsigned p[4];
#pragma unroll
        for (int k = 0; k < 4; ++k) {
            const int e = j + k;
            p[k] = edges[(e < end) ? e : (end - 1)];
        }
        uint2 u[4];
#pragma unroll
        for (int k = 0; k < 4; ++k)
            u[k] = *(const uint2*)&x[(size_t)(p[k] & 0xFFFFu) * 64 + fq * 4];
        float2 c[4];
#pragma unroll
        for (int k = 0; k < 4; ++k) {
            c[k] = *(const float2*)&scomp[((p[k] >> 16) & 7u) * 2];
            if (j + k >= end) { c[k].x = 0.f; c[k].y = 0.f; }
        }
#pragma unroll
        for (int k = 0; k < 4; ++k) {
            const float f0 = __uint_as_float(u[k].x << 16);
            const float f1 = __uint_as_float(u[k].x & 0xFFFF0000u);
            const float f2 = __uint_as_float(u[k].y << 16);
            const float f3 = __uint_as_float(u[k].y & 0xFFFF0000u);
            a0[0] = fmaf(c[k].x, f0, a0[0]); a1[0] = fmaf(c[k].y, f0, a1[0]);
            a0[1] = fmaf(c[k].x, f1, a0[1]); a1[1] = fmaf(c[k].y, f1, a1[1]);
            a0[2] = fmaf(c[k].x, f2, a0[2]); a1[2] = fmaf(c[k].y, f2, a1[2]);
            a0[3] = fmaf(c[k].x, f3, a0[3]); a1[3] = fmaf(c[k].y, f3, a1[3]);
        }
    }

    ushort4 s0 = { f2bf(a0[0]), f2bf(a0[1]), f2bf(a0[2]), f2bf(a0[3]) };
    ushort4 s1 = { f2bf(a1[0]), f2bf(a1[1]), f2bf(a1[2]), f2bf(a1[3]) };
    *(ushort4*)&y[(size_t)n * 128 + fq * 4]      = s0;
    *(ushort4*)&y[(size_t)n * 128 + 64 + fq * 4] = s1;
}

// ---------------------------------------------------------------------------
// MFMA node transform: h[0:64] = U[64x192] @ W[192x64] + bias, U=[y0,y1,x]
// bf16, W in registers (6 frags/wave). Wave w owns output cols [16w,16w+16).
//  !FUSE: writes relu(h) bf16.  FUSE: accumulates h . fc_w into scalar;
//  the last block to finish applies sigmoid and writes the output.
// ---------------------------------------------------------------------------
template <bool FUSE>
__global__ __launch_bounds__(256) void mfma_transform(
    const ushort_t* __restrict__ y_bf,   // [N,128]
    const ushort_t* __restrict__ x_bf,   // [N,64]
    const ushort_t* __restrict__ Wt,     // [64,192] this layer (n-major)
    const float* __restrict__ bias,      // [64] f32
    const float* __restrict__ fcw,       // [N*64] (FUSE)
    ushort_t* __restrict__ xout,         // [N,64] (!FUSE)
    float* __restrict__ scalar,          // [1]    (FUSE)
    const float* __restrict__ fcb,       // [1]    (FUSE)
    int* __restrict__ done,              // [1]    (FUSE)
    float* __restrict__ outp)            // [1]    (FUSE)
{
    __shared__ __align__(16) ushort_t su[64 * 200];   // 200 = 192 + 8 pad
    __shared__ float sred[4];
    const int t = threadIdx.x;
    const int w = t >> 6;
    const int lane = t & 63;
    const int c16 = lane & 15;
    const int quad = lane >> 4;
    const int tile = blockIdx.x;

    bf16x8 wf[6];
#pragma unroll
    for (int kf = 0; kf < 6; ++kf)
        wf[kf] = *(const bf16x8*)&Wt[(w * 16 + c16) * 192 + kf * 32 + quad * 8];
    const float bv = bias[w * 16 + c16];

#pragma unroll
    for (int k = 0; k < 6; ++k) {
        const int cid = t + 256 * k;          // 0..1535
        const int row = cid / 24;
        const int part = cid % 24;
        const int n = tile * 64 + row;
        uint4 v = {0u, 0u, 0u, 0u};
        if (n < N_NODES) {
            v = (part < 16) ? *(const uint4*)&y_bf[(size_t)n * 128 + part * 8]
                            : *(const uint4*)&x_bf[(size_t)n * 64 + (part - 16) * 8];
        }
        *(uint4*)&su[row * 200 + part * 8] = v;
    }
    __syncthreads();

    float fsum = 0.f;
#pragma unroll
    for (int mt = 0; mt < 4; ++mt) {
        f32x4 acc = {bv, bv, bv, bv};
#pragma unroll
        for (int kf = 0; kf < 6; ++kf) {
            const bf16x8 af =
                *(const bf16x8*)&su[(mt * 16 + c16) * 200 + kf * 32 + quad * 8];
            acc = __builtin_amdgcn_mfma_f32_16x16x32_bf16(af, wf[kf], acc, 0, 0, 0);
        }
        const int nodeb = tile * 64 + mt * 16 + quad * 4;
        if (FUSE) {
#pragma unroll
            for (int r = 0; r < 4; ++r) {
                const int n = nodeb + r;
                if (n < N_NODES)
                    fsum += acc[r] * fcw[(size_t)n * 64 + w * 16 + c16];
            }
        } else {
#pragma unroll
            for (int r = 0; r < 4; ++r) {
                const int n = nodeb + r;
                if (n < N_NODES)
                    xout[(size_t)n * 64 + w * 16 + c16] = f2bf(fmaxf(acc[r], 0.f));
            }
        }
    }

    if (FUSE) {
#pragma unroll
        for (int off = 32; off; off >>= 1) fsum += __shfl_down(fsum, off, 64);
        if (lane == 0) sred[w] = fsum;
        __syncthreads();
        if (t == 0) {
            atomicAdd(scalar, sred[0] + sred[1] + sred[2] + sred[3]);
            __threadfence();
            const int ticket = atomicAdd(done, 1);
            if (ticket == (int)gridDim.x - 1) {
                const float v = atomicAdd(scalar, 0.0f) + fcb[0];
                outp[0] = 1.0f / (1.0f + expf(-v));
            }
        }
    }
}

// ---------------------------------------------------------------------------
extern "C" void kernel_launch(void* const* d_in, const int* in_sizes, int n_in,
                              void* d_out, int out_size, void* d_ws, size_t ws_size,
                              hipStream_t stream)
{
    const float* features = (const float*)d_in[0];  // [50000, 64]
    const float* V        = (const float*)d_in[1];  // [2, 2, 64, 64]
    const float* comp     = (const float*)d_in[2];  // [2, 8, 2]
    const float* loop_w   = (const float*)d_in[3];  // [2, 64, 64]
    const float* bias     = (const float*)d_in[4];  // [2, 64]
    const float* fc_w     = (const float*)d_in[5];  // [1, 50000*64]
    const float* fc_b     = (const float*)d_in[6];  // [1]
    const int*   src      = (const int*)d_in[7];
    const int*   dst      = (const int*)d_in[8];
    const int*   etype    = (const int*)d_in[9];
    float* out = (float*)d_out;

    char* ws = (char*)d_ws;
    ushort_t*     y_bf    = (ushort_t*)(ws);                 // 12,800,000 B
    ushort_t*     x_bf    = (ushort_t*)(ws + 12800000);      //  6,400,000 B
    ushort_t*     x1_bf   = (ushort_t*)(ws + 19200000);      //  6,400,000 B
    ushort_t*     Wt      = (ushort_t*)(ws + 25600000);      //     49,152 B
    float*        scalar  = (float*)   (ws + 25649152);      //          4 B
    int*          done    = (int*)     (ws + 25649156);      //          4 B
    int*          bucketFill = (int*)  (ws + 25649280);      //      1,568 B
    int*          row_ptr = (int*)     (ws + 25650944);      //    200,004 B
    unsigned int* edges   = (unsigned int*)(ws + 25851008);  //  3,200,000 B
    unsigned int* buf     = (unsigned int*)(ws + 29051008);  //  4,816,896 B
                                                             // end ~33.9 MB

    const int aggBlocks = N_NODES / 16;             // 3125 (exact)
    const int mtBlocks  = (N_NODES + 63) / 64;      // 782
    const int k1Blocks  = (N_EDGES + 2047) / 2048;  // 391

    // ---- prep (bf16 converts + zero counters) + bucketed CSR build ----
    prep_kernel<<<3222, 256, 0, stream>>>(features, x_bf, V, loop_w, Wt,
                                          bucketFill, scalar, done);
    bucket_scatter<<<k1Blocks, 256, 0, stream>>>(src, dst, etype, bucketFill, buf);
    bucket_sort<<<NBUCKET, 256, 0, stream>>>(buf, bucketFill, edges, row_ptr);

    // ---- layer 0 ----
    aggregate_v4<<<aggBlocks, 256, 0, stream>>>(x_bf, edges, row_ptr, comp, y_bf);
    mfma_transform<false><<<mtBlocks, 256, 0, stream>>>(
        y_bf, x_bf, Wt, bias, nullptr, x1_bf, nullptr, nullptr, nullptr, nullptr);

    // ---- layer 1 + fused FC dot + last-block sigmoid ----
    aggregate_v4<<<aggBlocks, 256, 0, stream>>>(x1_bf, edges, row_ptr, comp + 16, y_bf);
    mfma_transform<true><<<mtBlocks, 256, 0, stream>>>(
        y_bf, x1_bf, Wt + 12288, bias + 64, fc_w, nullptr, scalar, fc_b, done, out);
}